// Round 8
// baseline (278.408 us; speedup 1.0000x reference)
//
#include <hip/hip_runtime.h>
#include <hip/hip_bf16.h>
#include <math.h>

typedef unsigned int  u32;
typedef unsigned short u16;
typedef unsigned long long u64;

using bf16x8  = __attribute__((ext_vector_type(8))) __bf16;
using float4v = __attribute__((ext_vector_type(4))) float;

#define MFMA16(a,b,c) __builtin_amdgcn_mfma_f32_16x16x32_bf16(a,b,c,0,0,0)

// ---- fast-path workspace layout (bytes) — total 338 KB ----
#define W1P_OFF   0u          // 12288 u16
#define W2P_OFF   24576u      // 4096 u16
#define GWP_OFF   40960u      // 1024 u16 (gate padded to m=16)
#define E1P_OFF   43008u      // 65536 u16 (4 experts x 16384)
#define E2P_OFF   174080u     // 65536 u16 (4 experts x 16384)
#define ZF_OFF    305152u     // 8192 f32
#define CNTF_OFF  337920u     // 4 u32
#define PSUMF_OFF 337984u     // 4 f32
#define FAST_WS_BYTES 338048u

// fallback (R3) layout
#define Z_OFF    0u
#define CNT_OFF  32768u
#define PSUM_OFF 32832u

__device__ inline u16 f2bf(float f){
  union { float f; u32 u; } v; v.f = f;
  u32 r = v.u + 0x7fffu + ((v.u >> 16) & 1u);   // RNE
  return (u16)(r >> 16);
}
// packed RNE pair convert (v_cvt_pk_bf16_f32)
__device__ inline u32 pk2(float a, float b){
  union { __hip_bfloat162 h2; u32 u; } v;
  v.h2 = __float22bfloat162_rn(make_float2(a, b));
  return v.u;
}

// GELU via A&S 7.1.26 erf, branchless, raw v_rcp (|err|~1e-7 << bf16 ulp).
__device__ inline float geluf(float x){
  float u = fabsf(x) * 0.70710678118654752f;
  float t = __builtin_amdgcn_rcpf(1.0f + 0.3275911f * u);
  float poly = t*(0.254829592f + t*(-0.284496736f +
               t*(1.421413741f + t*(-1.453152027f + t*1.061405429f))));
  float er = 1.0f - poly * __expf(-u*u);
  return 0.5f * x * (1.0f + copysignf(er, x));
}

// ================= k0 v3: one thread per 16B dest fragment ============================
// Reads: 8 gathered f32 per thread (per-instr across a wave: 4 x 64B segments).
// Writes: one uint4 per thread, fully coalesced. 26760 threads -> 105 blocks.
__global__ __launch_bounds__(256) void k0_pack(
    const float* __restrict__ w1, const float* __restrict__ w2, const float* __restrict__ gw,
    const float* __restrict__ e1, const float* __restrict__ e2,
    u16* w1p, u16* w2p, u16* gwp, u16* e1p, u16* e2p,
    float* z, u32* cnt, float* psum)
{
  int d = blockIdx.x*256 + threadIdx.x;
  int lane = d & 63, col = lane & 15, q = lane >> 4;
  if (d < 1536){                          // w1 [192][64]: tiles kc*4+mt (kc<6)
    int tile = d >> 6, kc = tile >> 2, mt = tile & 3;
    int m = mt*16 + col, k0 = kc*32 + q*8;
    uint4 v;
    v.x = pk2(w1[(k0+0)*64+m], w1[(k0+1)*64+m]);
    v.y = pk2(w1[(k0+2)*64+m], w1[(k0+3)*64+m]);
    v.z = pk2(w1[(k0+4)*64+m], w1[(k0+5)*64+m]);
    v.w = pk2(w1[(k0+6)*64+m], w1[(k0+7)*64+m]);
    *(uint4*)(w1p + d*8) = v; return;
  }
  d -= 1536;
  if (d < 512){                           // w2 [64][64]: tiles kc*4+mt (kc<2)
    int tile = d >> 6, kc = tile >> 2, mt = tile & 3;
    int m = mt*16 + col, k0 = kc*32 + q*8;
    uint4 v;
    v.x = pk2(w2[(k0+0)*64+m], w2[(k0+1)*64+m]);
    v.y = pk2(w2[(k0+2)*64+m], w2[(k0+3)*64+m]);
    v.z = pk2(w2[(k0+4)*64+m], w2[(k0+5)*64+m]);
    v.w = pk2(w2[(k0+6)*64+m], w2[(k0+7)*64+m]);
    *(uint4*)(w2p + d*8) = v; return;
  }
  d -= 512;
  if (d < 128){                           // gw [64][4], zero-pad m to 16
    int kc = d >> 6, k0 = kc*32 + q*8;
    uint4 v = {0u,0u,0u,0u};
    if (col < 4){
      v.x = pk2(gw[(k0+0)*4+col], gw[(k0+1)*4+col]);
      v.y = pk2(gw[(k0+2)*4+col], gw[(k0+3)*4+col]);
      v.z = pk2(gw[(k0+4)*4+col], gw[(k0+5)*4+col]);
      v.w = pk2(gw[(k0+6)*4+col], gw[(k0+7)*4+col]);
    }
    *(uint4*)(gwp + d*8) = v; return;
  }
  d -= 128;
  if (d < 8192){                          // e1 [e][64][256]: per e tiles kc*16+mt (kc<2)
    int e = d >> 11, t2 = d & 2047;
    int tile = t2 >> 6, kc = tile >> 4, mt = tile & 15;
    int m = mt*16 + col, k0 = kc*32 + q*8;
    const float* s = e1 + e*16384;
    uint4 v;
    v.x = pk2(s[(k0+0)*256+m], s[(k0+1)*256+m]);
    v.y = pk2(s[(k0+2)*256+m], s[(k0+3)*256+m]);
    v.z = pk2(s[(k0+4)*256+m], s[(k0+5)*256+m]);
    v.w = pk2(s[(k0+6)*256+m], s[(k0+7)*256+m]);
    *(uint4*)(e1p + d*8) = v; return;
  }
  d -= 8192;
  if (d < 8192){                          // e2 [e][256][64]: per e tiles kc*4+mt (kc<8)
    int e = d >> 11, t2 = d & 2047;
    int tile = t2 >> 6, kc = tile >> 2, mt = tile & 3;
    int m = mt*16 + col, k0 = kc*32 + q*8;
    const float* s = e2 + e*16384;
    uint4 v;
    v.x = pk2(s[(k0+0)*64+m], s[(k0+1)*64+m]);
    v.y = pk2(s[(k0+2)*64+m], s[(k0+3)*64+m]);
    v.z = pk2(s[(k0+4)*64+m], s[(k0+5)*64+m]);
    v.w = pk2(s[(k0+6)*64+m], s[(k0+7)*64+m]);
    *(uint4*)(e2p + d*8) = v; return;
  }
  d -= 8192;
  if (d < 8192){ z[d] = 0.f; return; }
  d -= 8192;
  if (d < 4){ cnt[d] = 0u; return; }
  d -= 4;
  if (d < 4){ psum[d] = 0.f; return; }
}

// ================= kMain: 3 barriers, two-half x staging, ~24 KB LDS ==================
__global__ __launch_bounds__(256) void kMain(
    const float* __restrict__ x,
    const float* __restrict__ b1, const float* __restrict__ b2, const float* __restrict__ gb,
    const u16* __restrict__ w1p, const u16* __restrict__ w2p, const u16* __restrict__ gwp,
    const u16* __restrict__ e1p, const u16* __restrict__ e2p,
    const float* __restrict__ eb1, const float* __restrict__ eb2,
    float* __restrict__ z, u32* __restrict__ cnt, float* __restrict__ psum)
{
  __shared__ char wreg[13312];    // 4 waves x 3328B: x half-stage -> h1 -> hid -> partials
  __shared__ char hl[9216];       // 64 rows x 144B (published at barrier 1)
  __shared__ int   be_s[64];
  __shared__ float gv_s[64];
  __shared__ int   sperm[64];
  __shared__ int   se_s[64];
  __shared__ float sg_s[64];
  __shared__ float lgp[4];
  __shared__ u32   lgc[4];

  const int tid  = threadIdx.x;
  const int lane = tid & 63, wave = tid >> 6;
  const int col  = lane & 15, quad = lane >> 4;
  const int tok0 = blockIdx.x * 64;
  const int t    = wave*16 + col;          // own token slot in block
  if (tid < 4){ lgp[tid] = 0.f; lgc[tid] = 0u; }

  char* wr = wreg + wave*3328;

  // ---- stage own 16 tokens in 2 halves (96 floats each), coalesced, no barrier ----
  // half rows: 12 x 16B chunks, 208B stride. Same-wave DS ordering makes the
  // write -> read -> overwrite -> read sequence safe without barriers.
  const float* xw = x + (size_t)(tok0 + wave*16)*192;
  bf16x8 bx[6];
  for (int h = 0; h < 2; ++h){
    for (int it = 0; it < 3; ++it){
      int task = it*64 + lane;             // 192 tasks: 16 rows x 12 chunks
      int tr = task / 12, c = task % 12;
      const float* src = xw + tr*192 + h*96 + c*8;
      float4 f0 = *(const float4*)(src);
      float4 f1 = *(const float4*)(src + 4);
      uint4 v;
      v.x = pk2(f0.x,f0.y); v.y = pk2(f0.z,f0.w);
      v.z = pk2(f1.x,f1.y); v.w = pk2(f1.z,f1.w);
      *(uint4*)(wr + tr*208 + c*16) = v;
    }
    for (int kc = 0; kc < 3; ++kc)
      bx[h*3 + kc] = *(const bf16x8*)(wr + col*208 + (4*kc + quad)*16);
  }

  // ---- GEMM1: h1T = gelu(W1^T x + b1) -> wave-private h1 tile (reuses stage space) ----
  char* h1t = wr;                          // 16 rows x 144B
  for (int mt = 0; mt < 4; ++mt){
    float4v acc = {0.f,0.f,0.f,0.f};
    for (int kc = 0; kc < 6; ++kc){
      bf16x8 a = *(const bf16x8*)(w1p + ((kc*4 + mt)*64 + lane)*8);
      acc = MFMA16(a, bx[kc], acc);
    }
    int j0 = mt*16 + quad*4;
    float4 bb = *(const float4*)(b1 + j0);
    uint2 w; w.x = pk2(geluf(acc[0]+bb.x), geluf(acc[1]+bb.y));
             w.y = pk2(geluf(acc[2]+bb.z), geluf(acc[3]+bb.w));
    *(uint2*)(h1t + col*144 + mt*32 + quad*8) = w;
  }

  // ---- GEMM2: hT = W2^T h1 + b2 -> hl own rows ----
  {
    bf16x8 bh1[2];
    for (int kc = 0; kc < 2; ++kc)
      bh1[kc] = *(const bf16x8*)(h1t + col*144 + (4*kc+quad)*16);
    for (int mt = 0; mt < 4; ++mt){
      float4v acc = {0.f,0.f,0.f,0.f};
      for (int kc = 0; kc < 2; ++kc){
        bf16x8 a = *(const bf16x8*)(w2p + ((kc*4 + mt)*64 + lane)*8);
        acc = MFMA16(a, bh1[kc], acc);
      }
      int j0 = mt*16 + quad*4;
      float4 bb = *(const float4*)(b2 + j0);
      uint2 w; w.x = pk2(acc[0]+bb.x, acc[1]+bb.y);
               w.y = pk2(acc[2]+bb.z, acc[3]+bb.w);
      *(uint2*)(hl + t*144 + mt*32 + quad*8) = w;
    }
  }

  // ---- gate via MFMA on own hl row; routing by quad-0 lanes (atomics deferred) ----
  float p0=0.f,p1=0.f,p2=0.f,p3=0.f; int be=0;
  {
    bf16x8 bh[2];
    for (int kc = 0; kc < 2; ++kc)
      bh[kc] = *(const bf16x8*)(hl + t*144 + (4*kc+quad)*16);
    float4v ag = {0.f,0.f,0.f,0.f};
    for (int kc = 0; kc < 2; ++kc){
      bf16x8 a = *(const bf16x8*)(gwp + (kc*64 + lane)*8);
      ag = MFMA16(a, bh[kc], ag);
    }
    if (quad == 0){
      float l0 = ag[0]+gb[0], l1 = ag[1]+gb[1], l2 = ag[2]+gb[2], l3 = ag[3]+gb[3];
      float mx = fmaxf(fmaxf(l0,l1), fmaxf(l2,l3));
      float x0 = __expf(l0-mx), x1 = __expf(l1-mx), x2 = __expf(l2-mx), x3 = __expf(l3-mx);
      float inv = __builtin_amdgcn_rcpf(x0+x1+x2+x3);
      p0 = x0*inv; p1 = x1*inv; p2 = x2*inv; p3 = x3*inv;
      float bv = l0; be = 0;
      if (l1 > bv){ bv = l1; be = 1; }
      if (l2 > bv){ bv = l2; be = 2; }
      if (l3 > bv){ bv = l3; be = 3; }
      be_s[t] = be;
      gv_s[t] = (be==0) ? p0 : (be==1) ? p1 : (be==2) ? p2 : p3;
    }
  }
  __syncthreads();                         // barrier 1: hl + routing published
  if (quad == 0){
    atomicAdd(&lgp[0], p0); atomicAdd(&lgp[1], p1);
    atomicAdd(&lgp[2], p2); atomicAdd(&lgp[3], p3);
    atomicAdd(&lgc[be], 1u);
  }

  // ---- wave 0: stable sort of 64 tokens by expert via ballot ranks ----
  if (tid < 64){
    int e = be_s[tid];
    u64 m0 = __ballot(e==0), m1 = __ballot(e==1), m2 = __ballot(e==2), m3 = __ballot(e==3);
    int c0 = __popcll(m0), c1 = __popcll(m1), c2 = __popcll(m2);
    int base = (e==0) ? 0 : (e==1) ? c0 : (e==2) ? c0+c1 : c0+c1+c2;
    u64 me = (e==0) ? m0 : (e==1) ? m1 : (e==2) ? m2 : m3;
    int pos = base + __popcll(me & ((1ull<<tid)-1ull));
    sperm[pos] = tid; se_s[pos] = e; sg_s[pos] = gv_s[tid];
  }
  __syncthreads();                         // barrier 2

  // ---- per-wave expert loop on sorted 16-token slice (quarter-pass hid, no barriers)
  const int slice = wave*16;
  const int tt    = sperm[slice + col];
  const int myE   = se_s[slice + col];
  const float myG = sg_s[slice + col];
  const int e_lo  = se_s[slice], e_hi = se_s[slice + 15];
  char* hbt = wr;                          // wave-private 16 x 144B hid quarter tile

  bf16x8 bhp[2];
  for (int kc = 0; kc < 2; ++kc)
    bhp[kc] = *(const bf16x8*)(hl + tt*144 + (4*kc+quad)*16);

  float oacc[16];
  for (int i = 0; i < 16; ++i) oacc[i] = 0.f;

  for (int e = e_lo; e <= e_hi; ++e){
    const u16* W1 = e1p + e*16384;
    const u16* W2 = e2p + e*16384;
    float4v accE[4];
    for (int mt = 0; mt < 4; ++mt) accE[mt] = (float4v){0.f,0.f,0.f,0.f};
    for (int p = 0; p < 4; ++p){
      for (int mt2 = 0; mt2 < 4; ++mt2){
        float4v acc = {0.f,0.f,0.f,0.f};
        for (int kc = 0; kc < 2; ++kc){
          bf16x8 a = *(const bf16x8*)(W1 + ((kc*16 + p*4 + mt2)*64 + lane)*8);
          acc = MFMA16(a, bhp[kc], acc);
        }
        int j0 = p*64 + mt2*16 + quad*4;
        float4 bb = *(const float4*)(eb1 + e*256 + j0);
        uint2 w; w.x = pk2(geluf(acc[0]+bb.x), geluf(acc[1]+bb.y));
                 w.y = pk2(geluf(acc[2]+bb.z), geluf(acc[3]+bb.w));
        *(uint2*)(hbt + col*144 + mt2*32 + quad*8) = w;
      }
      bf16x8 bq0 = *(const bf16x8*)(hbt + col*144 + quad*16);
      bf16x8 bq1 = *(const bf16x8*)(hbt + col*144 + (4+quad)*16);
      for (int mt = 0; mt < 4; ++mt){
        bf16x8 a0 = *(const bf16x8*)(W2 + (((p*2+0)*4 + mt)*64 + lane)*8);
        bf16x8 a1 = *(const bf16x8*)(W2 + (((p*2+1)*4 + mt)*64 + lane)*8);
        accE[mt] = MFMA16(a0, bq0, accE[mt]);
        accE[mt] = MFMA16(a1, bq1, accE[mt]);
      }
    }
    float wgt = (myE == e) ? myG : 0.f;
    for (int mt = 0; mt < 4; ++mt){
      float4 bb = *(const float4*)(eb2 + e*64 + mt*16 + quad*4);
      oacc[mt*4+0] += (accE[mt][0] + bb.x) * wgt;
      oacc[mt*4+1] += (accE[mt][1] + bb.y) * wgt;
      oacc[mt*4+2] += (accE[mt][2] + bb.z) * wgt;
      oacc[mt*4+3] += (accE[mt][3] + bb.w) * wgt;
    }
  }

  // ---- pooled reduction over 16 cols; partials into wave region ----
  for (int m = 1; m < 16; m <<= 1)
    for (int i = 0; i < 16; ++i)
      oacc[i] += __shfl_xor(oacc[i], m, 64);
  if (col == 0){
    float* pw = (float*)wr;
    for (int mt = 0; mt < 4; ++mt)
      for (int r = 0; r < 4; ++r)
        pw[mt*16 + quad*4 + r] = oacc[mt*4 + r];
  }
  __syncthreads();                         // barrier 3
  int b = blockIdx.x >> 4;                 // 16 blocks per batch row
  if (tid < 64){
    float s = *(const float*)(wreg + tid*4)        + *(const float*)(wreg + 3328 + tid*4)
            + *(const float*)(wreg + 6656 + tid*4) + *(const float*)(wreg + 9984 + tid*4);
    atomicAdd(&z[b*64 + tid], s);
  }
  if (tid < 4){ atomicAdd(&cnt[tid], lgc[tid]); atomicAdd(&psum[tid], lgp[tid]); }
}

// ================= kFinal: mean pool + LayerNorm + classifier (+aux) ==================
__global__ __launch_bounds__(64) void kFinal(
    const float* __restrict__ z, const u32* __restrict__ cnt, const float* __restrict__ psum,
    const float* __restrict__ ln_g, const float* __restrict__ ln_b,
    const float* __restrict__ cw1, const float* __restrict__ cb1,
    const float* __restrict__ cw2, const float* __restrict__ cb2,
    float* __restrict__ out)
{
  __shared__ float z_l[64], zn_l[64], c1_l[64], red[2];
  int tid = threadIdx.x, b = blockIdx.x;
  z_l[tid] = z[b*64 + tid] * (1.0f/1024.0f);
  __syncthreads();
  if (tid == 0){
    float mu = 0.f; for (int i=0;i<64;++i) mu += z_l[i]; mu *= (1.f/64.f);
    float vv = 0.f; for (int i=0;i<64;++i){ float d=z_l[i]-mu; vv += d*d; } vv *= (1.f/64.f);
    red[0]=mu; red[1]=1.0f/sqrtf(vv+1e-5f);
  }
  __syncthreads();
  zn_l[tid] = (z_l[tid]-red[0])*red[1]*ln_g[tid] + ln_b[tid];
  __syncthreads();
  float a1 = cb1[tid];
  for (int k=0;k<64;++k) a1 += zn_l[k]*cw1[k*64+tid];
  c1_l[tid] = geluf(a1);
  __syncthreads();
  if (tid < 10){
    float y = cb2[tid];
    for (int k=0;k<64;++k) y += c1_l[k]*cw2[k*10+tid];
    out[b*10+tid] = y;
  }
  if (b == 0 && tid == 0){
    float aux = 0.f;
    for (int e=0;e<4;++e) aux += (float)cnt[e]*psum[e];
    out[1280] = 4.0f*aux/(131072.0f*131072.0f);
  }
}

// ================= fallback path (verified R3 fp32 kernels) ===========================
__global__ __launch_bounds__(256) void kInitF(float* z, u32* cnt, float* psum){
  int i = blockIdx.x*256 + threadIdx.x;
  if (i < 8192) z[i] = 0.f;
  if (i < 4){ cnt[i] = 0u; psum[i] = 0.f; }
}

__global__ __launch_bounds__(256) void kFusedF(
    const float* __restrict__ x,
    const float* __restrict__ w1, const float* __restrict__ b1,
    const float* __restrict__ w2, const float* __restrict__ b2,
    const float* __restrict__ gw, const float* __restrict__ gb,
    const float* __restrict__ e1, const float* __restrict__ eb1,
    const float* __restrict__ e2, const float* __restrict__ eb2,
    float* __restrict__ z, u32* __restrict__ cnt, float* __restrict__ psum)
{
  __shared__ float xs[4][192];
  __shared__ float h1s[4][64];
  __shared__ float hs[4][64];
  __shared__ float hid[4][256];
  __shared__ float lg[4][4];
  __shared__ int   be_s[4];
  __shared__ float gv_s[4];
  __shared__ float lgp[4];
  __shared__ u32   lgc[4];
  const int tid  = threadIdx.x;
  const int w    = tid >> 6, lane = tid & 63;
  const int tok  = blockIdx.x*4 + w;
  if (tid < 4){ lgp[tid] = 0.f; lgc[tid] = 0u; }
  for (int r = 0; r < 3; ++r)
    xs[w][lane + 64*r] = x[(size_t)tok*192 + lane + 64*r];
  __syncthreads();
  float a = b1[lane];
  for (int k = 0; k < 192; ++k) a += xs[w][k]*w1[k*64 + lane];
  h1s[w][lane] = geluf(a);
  __syncthreads();
  float h = b2[lane];
  for (int k = 0; k < 64; ++k) h += h1s[w][k]*w2[k*64 + lane];
  hs[w][lane] = h;
  __syncthreads();
  if (lane < 4){
    float l = gb[lane];
    for (int k = 0; k < 64; ++k) l += hs[w][k]*gw[k*4 + lane];
    lg[w][lane] = l;
  }
  __syncthreads();
  if (lane == 0){
    float l0=lg[w][0], l1=lg[w][1], l2=lg[w][2], l3=lg[w][3];
    float mx = fmaxf(fmaxf(l0,l1),fmaxf(l2,l3));
    float x0=expf(l0-mx), x1=expf(l1-mx), x2=expf(l2-mx), x3=expf(l3-mx);
    float inv = 1.f/(x0+x1+x2+x3);
    float p0=x0*inv, p1=x1*inv, p2=x2*inv, p3=x3*inv;
    int be=0; float bv=l0;
    if (l1>bv){bv=l1;be=1;}
    if (l2>bv){bv=l2;be=2;}
    if (l3>bv){bv=l3;be=3;}
    be_s[w]=be;
    gv_s[w]=(be==0)?p0:(be==1)?p1:(be==2)?p2:p3;
    atomicAdd(&lgp[0],p0); atomicAdd(&lgp[1],p1);
    atomicAdd(&lgp[2],p2); atomicAdd(&lgp[3],p3);
    atomicAdd(&lgc[be],1u);
  }
  __syncthreads();
  const int e    = be_s[w];
  const float gv = gv_s[w];
  const float* W1 = e1 + e*16384;
  const float* W2 = e2 + e*16384;
  for (int q = 0; q < 4; ++q){
    int j = q*64 + lane;
    float s = eb1[e*256 + j];
    for (int k = 0; k < 64; ++k) s += hs[w][k]*W1[k*256 + j];
    hid[w][j] = geluf(s);
  }
  __syncthreads();
  float o = eb2[e*64 + lane];
  for (int j = 0; j < 256; ++j) o += hid[w][j]*W2[j*64 + lane];
  int b = tok >> 10;
  atomicAdd(&z[b*64 + lane], o*gv);
  __syncthreads();
  if (tid < 4){ atomicAdd(&cnt[tid], lgc[tid]); atomicAdd(&psum[tid], lgp[tid]); }
}

// ======================================================================================
extern "C" void kernel_launch(void* const* d_in, const int* in_sizes, int n_in,
                              void* d_out, int out_size, void* d_ws, size_t ws_size,
                              hipStream_t stream)
{
  const float* x    = (const float*)d_in[0];
  const float* pw1  = (const float*)d_in[1];
  const float* pb1  = (const float*)d_in[2];
  const float* pw2  = (const float*)d_in[3];
  const float* pb2  = (const float*)d_in[4];
  const float* gw   = (const float*)d_in[5];
  const float* gb   = (const float*)d_in[6];
  const float* ew1  = (const float*)d_in[7];
  const float* eb1  = (const float*)d_in[8];
  const float* ew2  = (const float*)d_in[9];
  const float* eb2  = (const float*)d_in[10];
  const float* lng  = (const float*)d_in[11];
  const float* lnb  = (const float*)d_in[12];
  const float* cw1  = (const float*)d_in[13];
  const float* cb1  = (const float*)d_in[14];
  const float* cw2  = (const float*)d_in[15];
  const float* cb2  = (const float*)d_in[16];
  char* ws  = (char*)d_ws;
  float* out = (float*)d_out;

  if (ws_size >= FAST_WS_BYTES){
    u16*  w1p  = (u16*)(ws + W1P_OFF);
    u16*  w2p  = (u16*)(ws + W2P_OFF);
    u16*  gwp  = (u16*)(ws + GWP_OFF);
    u16*  e1p  = (u16*)(ws + E1P_OFF);
    u16*  e2p  = (u16*)(ws + E2P_OFF);
    float* z    = (float*)(ws + ZF_OFF);
    u32*  cnt  = (u32*)(ws + CNTF_OFF);
    float* psum = (float*)(ws + PSUMF_OFF);
    k0_pack<<<105, 256, 0, stream>>>(pw1, pw2, gw, ew1, ew2,
                                     w1p, w2p, gwp, e1p, e2p, z, cnt, psum);
    kMain <<<2048, 256, 0, stream>>>(x, pb1, pb2, gb, w1p, w2p, gwp, e1p, e2p,
                                     eb1, eb2, z, cnt, psum);
    kFinal<<<128, 64, 0, stream>>>(z, cnt, psum, lng, lnb, cw1, cb1, cw2, cb2, out);
  } else {
    float* z    = (float*)(ws + Z_OFF);
    u32*   cnt  = (u32*)(ws + CNT_OFF);
    float* psum = (float*)(ws + PSUM_OFF);
    kInitF <<<32,    256, 0, stream>>>(z, cnt, psum);
    kFusedF<<<32768, 256, 0, stream>>>(x, pw1, pb1, pw2, pb2, gw, gb,
                                       ew1, eb1, ew2, eb2, z, cnt, psum);
    kFinal <<<128,   64,  0, stream>>>(z, cnt, psum, lng, lnb, cw1, cb1, cw2, cb2, out);
  }
}

// Round 9
// 241.315 us; speedup vs baseline: 1.1537x; 1.1537x over previous
//
#include <hip/hip_runtime.h>
#include <hip/hip_bf16.h>
#include <math.h>

typedef unsigned int  u32;
typedef unsigned short u16;
typedef unsigned long long u64;

using bf16x8  = __attribute__((ext_vector_type(8))) __bf16;
using float4v = __attribute__((ext_vector_type(4))) float;

#define MFMA16(a,b,c) __builtin_amdgcn_mfma_f32_16x16x32_bf16(a,b,c,0,0,0)

// ---- fast-path workspace layout (bytes) — total 338 KB ----
#define W1P_OFF   0u          // 12288 u16
#define W2P_OFF   24576u      // 4096 u16
#define GWP_OFF   40960u      // 1024 u16 (gate padded to m=16)
#define E1P_OFF   43008u      // 65536 u16 (4 experts x 16384)
#define E2P_OFF   174080u     // 65536 u16 (4 experts x 16384)
#define ZF_OFF    305152u     // 8192 f32
#define CNTF_OFF  337920u     // 4 u32
#define PSUMF_OFF 337984u     // 4 f32
#define FAST_WS_BYTES 338048u

// fallback (R3) layout
#define Z_OFF    0u
#define CNT_OFF  32768u
#define PSUM_OFF 32832u

__device__ inline u16 f2bf(float f){
  union { float f; u32 u; } v; v.f = f;
  u32 r = v.u + 0x7fffu + ((v.u >> 16) & 1u);   // RNE
  return (u16)(r >> 16);
}
__device__ inline u32 pk2(float a, float b){
  union { __hip_bfloat162 h2; u32 u; } v;
  v.h2 = __float22bfloat162_rn(make_float2(a, b));
  return v.u;
}
// GELU via A&S 7.1.26 erf, branchless (|err|~1e-7 << bf16 ulp).
__device__ inline float geluf(float x){
  float u = fabsf(x) * 0.70710678118654752f;
  float t = __builtin_amdgcn_rcpf(1.0f + 0.3275911f * u);
  float poly = t*(0.254829592f + t*(-0.284496736f +
               t*(1.421413741f + t*(-1.453152027f + t*1.061405429f))));
  float er = 1.0f - poly * __expf(-u*u);
  return 0.5f * x * (1.0f + copysignf(er, x));
}

// ================= k0 v3: one thread per 16B dest fragment (unchanged, R8) ============
__global__ __launch_bounds__(256) void k0_pack(
    const float* __restrict__ w1, const float* __restrict__ w2, const float* __restrict__ gw,
    const float* __restrict__ e1, const float* __restrict__ e2,
    u16* w1p, u16* w2p, u16* gwp, u16* e1p, u16* e2p,
    float* z, u32* cnt, float* psum)
{
  int d = blockIdx.x*256 + threadIdx.x;
  int lane = d & 63, col = lane & 15, q = lane >> 4;
  if (d < 1536){
    int tile = d >> 6, kc = tile >> 2, mt = tile & 3;
    int m = mt*16 + col, k0 = kc*32 + q*8;
    uint4 v;
    v.x = pk2(w1[(k0+0)*64+m], w1[(k0+1)*64+m]);
    v.y = pk2(w1[(k0+2)*64+m], w1[(k0+3)*64+m]);
    v.z = pk2(w1[(k0+4)*64+m], w1[(k0+5)*64+m]);
    v.w = pk2(w1[(k0+6)*64+m], w1[(k0+7)*64+m]);
    *(uint4*)(w1p + d*8) = v; return;
  }
  d -= 1536;
  if (d < 512){
    int tile = d >> 6, kc = tile >> 2, mt = tile & 3;
    int m = mt*16 + col, k0 = kc*32 + q*8;
    uint4 v;
    v.x = pk2(w2[(k0+0)*64+m], w2[(k0+1)*64+m]);
    v.y = pk2(w2[(k0+2)*64+m], w2[(k0+3)*64+m]);
    v.z = pk2(w2[(k0+4)*64+m], w2[(k0+5)*64+m]);
    v.w = pk2(w2[(k0+6)*64+m], w2[(k0+7)*64+m]);
    *(uint4*)(w2p + d*8) = v; return;
  }
  d -= 512;
  if (d < 128){
    int kc = d >> 6, k0 = kc*32 + q*8;
    uint4 v = {0u,0u,0u,0u};
    if (col < 4){
      v.x = pk2(gw[(k0+0)*4+col], gw[(k0+1)*4+col]);
      v.y = pk2(gw[(k0+2)*4+col], gw[(k0+3)*4+col]);
      v.z = pk2(gw[(k0+4)*4+col], gw[(k0+5)*4+col]);
      v.w = pk2(gw[(k0+6)*4+col], gw[(k0+7)*4+col]);
    }
    *(uint4*)(gwp + d*8) = v; return;
  }
  d -= 128;
  if (d < 8192){
    int e = d >> 11, t2 = d & 2047;
    int tile = t2 >> 6, kc = tile >> 4, mt = tile & 15;
    int m = mt*16 + col, k0 = kc*32 + q*8;
    const float* s = e1 + e*16384;
    uint4 v;
    v.x = pk2(s[(k0+0)*256+m], s[(k0+1)*256+m]);
    v.y = pk2(s[(k0+2)*256+m], s[(k0+3)*256+m]);
    v.z = pk2(s[(k0+4)*256+m], s[(k0+5)*256+m]);
    v.w = pk2(s[(k0+6)*256+m], s[(k0+7)*256+m]);
    *(uint4*)(e1p + d*8) = v; return;
  }
  d -= 8192;
  if (d < 8192){
    int e = d >> 11, t2 = d & 2047;
    int tile = t2 >> 6, kc = tile >> 2, mt = tile & 3;
    int m = mt*16 + col, k0 = kc*32 + q*8;
    const float* s = e2 + e*16384;
    uint4 v;
    v.x = pk2(s[(k0+0)*64+m], s[(k0+1)*64+m]);
    v.y = pk2(s[(k0+2)*64+m], s[(k0+3)*64+m]);
    v.z = pk2(s[(k0+4)*64+m], s[(k0+5)*64+m]);
    v.w = pk2(s[(k0+6)*64+m], s[(k0+7)*64+m]);
    *(uint4*)(e2p + d*8) = v; return;
  }
  d -= 8192;
  if (d < 8192){ z[d] = 0.f; return; }
  d -= 8192;
  if (d < 4){ cnt[d] = 0u; return; }
  d -= 4;
  if (d < 4){ psum[d] = 0.f; return; }
}

// ================= kMain v2: 256 tokens/block, 4 groups/wave, ILP x4 =================
__global__ __launch_bounds__(256, 2) void kMain(
    const float* __restrict__ x,
    const float* __restrict__ b1, const float* __restrict__ b2, const float* __restrict__ gb,
    const u16* __restrict__ w1p, const u16* __restrict__ w2p, const u16* __restrict__ gwp,
    const u16* __restrict__ e1p, const u16* __restrict__ e2p,
    const float* __restrict__ eb1, const float* __restrict__ eb2,
    float* __restrict__ z, u32* __restrict__ cnt, float* __restrict__ psum)
{
  __shared__ char hl[36864];      // 256 rows x 144B; after barrier 4: 4w x 4g x 2304B hid
  __shared__ char wreg[13312];    // 4 waves x 3328B: stage -> h1 -> partials
  __shared__ int   be_s[256];
  __shared__ float gv_s[256];
  __shared__ int   sperm[256];
  __shared__ int   se_s[256];
  __shared__ float sg_s[256];
  __shared__ int   cmat[4][4];    // [wave][expert] counts
  __shared__ float lgp[4];
  __shared__ u32   lgc[4];

  const int tid  = threadIdx.x;
  const int lane = tid & 63, wave = tid >> 6;
  const int col  = lane & 15, quad = lane >> 4;
  const int tok0 = blockIdx.x * 256;
  if (tid < 4){ lgp[tid] = 0.f; lgc[tid] = 0u; }

  char* wr = wreg + wave*3328;
  float gp0=0.f, gp1=0.f, gp2=0.f, gp3=0.f;
  int beg[4] = {0,0,0,0};

  // ================= front end: 4 groups of 16 tokens per wave =================
  for (int g = 0; g < 4; ++g){
    const int trow = wave*64 + g*16;
    const float* xw = x + (size_t)(tok0 + trow)*192;
    bf16x8 bx[6];
    for (int h = 0; h < 2; ++h){
      for (int it = 0; it < 3; ++it){
        int task = it*64 + lane;
        int tr = task / 12, c = task % 12;
        const float* src = xw + tr*192 + h*96 + c*8;
        float4 f0 = *(const float4*)(src);
        float4 f1 = *(const float4*)(src + 4);
        uint4 v;
        v.x = pk2(f0.x,f0.y); v.y = pk2(f0.z,f0.w);
        v.z = pk2(f1.x,f1.y); v.w = pk2(f1.z,f1.w);
        *(uint4*)(wr + tr*208 + c*16) = v;
      }
      for (int kc = 0; kc < 3; ++kc)
        bx[h*3+kc] = *(const bf16x8*)(wr + col*208 + (4*kc+quad)*16);
    }
    // GEMM1 -> wave-private h1 tile (reuses stage space)
    char* h1t = wr;
    for (int mt = 0; mt < 4; ++mt){
      float4v acc = {0.f,0.f,0.f,0.f};
      for (int kc = 0; kc < 6; ++kc){
        bf16x8 a = *(const bf16x8*)(w1p + ((kc*4+mt)*64 + lane)*8);
        acc = MFMA16(a, bx[kc], acc);
      }
      int j0 = mt*16 + quad*4;
      float4 bb = *(const float4*)(b1 + j0);
      uint2 wv; wv.x = pk2(geluf(acc[0]+bb.x), geluf(acc[1]+bb.y));
                wv.y = pk2(geluf(acc[2]+bb.z), geluf(acc[3]+bb.w));
      *(uint2*)(h1t + col*144 + mt*32 + quad*8) = wv;
    }
    // GEMM2 -> hl own row
    bf16x8 bh1[2];
    for (int kc = 0; kc < 2; ++kc)
      bh1[kc] = *(const bf16x8*)(h1t + col*144 + (4*kc+quad)*16);
    const int hrow = trow + col;
    for (int mt = 0; mt < 4; ++mt){
      float4v acc = {0.f,0.f,0.f,0.f};
      for (int kc = 0; kc < 2; ++kc){
        bf16x8 a = *(const bf16x8*)(w2p + ((kc*4+mt)*64 + lane)*8);
        acc = MFMA16(a, bh1[kc], acc);
      }
      int j0 = mt*16 + quad*4;
      float4 bb = *(const float4*)(b2 + j0);
      uint2 wv; wv.x = pk2(acc[0]+bb.x, acc[1]+bb.y);
                wv.y = pk2(acc[2]+bb.z, acc[3]+bb.w);
      *(uint2*)(hl + hrow*144 + mt*32 + quad*8) = wv;
    }
    // gate on own row
    bf16x8 bh[2];
    for (int kc = 0; kc < 2; ++kc)
      bh[kc] = *(const bf16x8*)(hl + hrow*144 + (4*kc+quad)*16);
    float4v ag = {0.f,0.f,0.f,0.f};
    for (int kc = 0; kc < 2; ++kc){
      bf16x8 a = *(const bf16x8*)(gwp + (kc*64+lane)*8);
      ag = MFMA16(a, bh[kc], ag);
    }
    if (quad == 0){
      float l0=ag[0]+gb[0], l1=ag[1]+gb[1], l2=ag[2]+gb[2], l3=ag[3]+gb[3];
      float mx = fmaxf(fmaxf(l0,l1),fmaxf(l2,l3));
      float x0=__expf(l0-mx), x1=__expf(l1-mx), x2=__expf(l2-mx), x3=__expf(l3-mx);
      float inv = __builtin_amdgcn_rcpf(x0+x1+x2+x3);
      float p0=x0*inv,p1=x1*inv,p2=x2*inv,p3=x3*inv;
      int be=0; float bv=l0;
      if (l1>bv){bv=l1;be=1;}
      if (l2>bv){bv=l2;be=2;}
      if (l3>bv){bv=l3;be=3;}
      be_s[hrow] = be;
      gv_s[hrow] = (be==0)?p0:(be==1)?p1:(be==2)?p2:p3;
      gp0+=p0; gp1+=p1; gp2+=p2; gp3+=p3;
      beg[g]=be;
    }
  }
  __syncthreads();                         // barrier 1: hl + routing published

  if (quad == 0){
    atomicAdd(&lgp[0],gp0); atomicAdd(&lgp[1],gp1);
    atomicAdd(&lgp[2],gp2); atomicAdd(&lgp[3],gp3);
    for (int g = 0; g < 4; ++g) atomicAdd(&lgc[beg[g]],1u);
  }

  // ============== block-wide stable sort of 256 tokens by expert ==============
  {
    int e = be_s[tid];                     // token id == tid
    u64 m0=__ballot(e==0), m1=__ballot(e==1), m2=__ballot(e==2), m3=__ballot(e==3);
    if (lane < 4){
      u64 mm = (lane==0)?m0:(lane==1)?m1:(lane==2)?m2:m3;
      cmat[wave][lane] = __popcll(mm);
    }
    u64 me = (e==0)?m0:(e==1)?m1:(e==2)?m2:m3;
    int r = __popcll(me & ((1ull<<lane)-1ull));
    __syncthreads();                       // barrier 2: cmat ready
    int base = 0;
    for (int ee = 0; ee < 4; ++ee)
      for (int w2_ = 0; w2_ < 4; ++w2_)
        if (ee < e || (ee == e && w2_ < wave)) base += cmat[w2_][ee];
    int pos = base + r;
    sperm[pos] = tid; se_s[pos] = e; sg_s[pos] = gv_s[tid];
  }
  __syncthreads();                         // barrier 3: sorted arrays ready

  // ============== expert loop: sorted 64-token slice, 4 groups, ILP x4 ==============
  const int sbase = wave*64;
  int myE[4]; float myG[4]; bf16x8 bhp[4][2];
  for (int g = 0; g < 4; ++g){
    int sp = sbase + g*16 + col;
    int tt = sperm[sp];
    myE[g] = se_s[sp]; myG[g] = sg_s[sp];
    for (int kc = 0; kc < 2; ++kc)
      bhp[g][kc] = *(const bf16x8*)(hl + tt*144 + (4*kc+quad)*16);
  }
  const int e_lo = se_s[sbase], e_hi = se_s[sbase+63];
  __syncthreads();                         // barrier 4: bhp extracted, hl reusable

  char* hb = hl + wave*9216;               // 4 groups x 2304B hid tiles
  float oacc[16];
  for (int i = 0; i < 16; ++i) oacc[i] = 0.f;

  for (int e = e_lo; e <= e_hi; ++e){
    const u16* W1 = e1p + e*16384;
    const u16* W2 = e2p + e*16384;
    float4v accD[4][4];                    // [mt][g]
    for (int mt = 0; mt < 4; ++mt)
      for (int g = 0; g < 4; ++g)
        accD[mt][g] = (float4v){0.f,0.f,0.f,0.f};
    for (int p = 0; p < 4; ++p){
      // L1 quarter (64 hid dims) for all 4 groups; A loaded once per mt2
      for (int mt2 = 0; mt2 < 4; ++mt2){
        bf16x8 a0 = *(const bf16x8*)(W1 + ((      p*4+mt2)*64 + lane)*8);
        bf16x8 a1 = *(const bf16x8*)(W1 + ((16 +  p*4+mt2)*64 + lane)*8);
        int j0 = p*64 + mt2*16 + quad*4;
        float4 bb = *(const float4*)(eb1 + e*256 + j0);
        for (int g = 0; g < 4; ++g){
          float4v acc = {0.f,0.f,0.f,0.f};
          acc = MFMA16(a0, bhp[g][0], acc);
          acc = MFMA16(a1, bhp[g][1], acc);
          uint2 wv; wv.x = pk2(geluf(acc[0]+bb.x), geluf(acc[1]+bb.y));
                    wv.y = pk2(geluf(acc[2]+bb.z), geluf(acc[3]+bb.w));
          *(uint2*)(hb + g*2304 + col*144 + mt2*32 + quad*8) = wv;
        }
      }
      // L2 quarter: consume; A loaded once per mt, 4 independent chains
      bf16x8 bq[4][2];
      for (int g = 0; g < 4; ++g){
        bq[g][0] = *(const bf16x8*)(hb + g*2304 + col*144 + quad*16);
        bq[g][1] = *(const bf16x8*)(hb + g*2304 + col*144 + (4+quad)*16);
      }
      for (int mt = 0; mt < 4; ++mt){
        bf16x8 a0 = *(const bf16x8*)(W2 + (((p*2+0)*4+mt)*64 + lane)*8);
        bf16x8 a1 = *(const bf16x8*)(W2 + (((p*2+1)*4+mt)*64 + lane)*8);
        for (int g = 0; g < 4; ++g){
          accD[mt][g] = MFMA16(a0, bq[g][0], accD[mt][g]);
          accD[mt][g] = MFMA16(a1, bq[g][1], accD[mt][g]);
        }
      }
    }
    for (int mt = 0; mt < 4; ++mt){
      float4 bb = *(const float4*)(eb2 + e*64 + mt*16 + quad*4);
      for (int g = 0; g < 4; ++g){
        float wgt = (myE[g]==e) ? myG[g] : 0.f;
        oacc[mt*4+0] += (accD[mt][g][0]+bb.x)*wgt;
        oacc[mt*4+1] += (accD[mt][g][1]+bb.y)*wgt;
        oacc[mt*4+2] += (accD[mt][g][2]+bb.z)*wgt;
        oacc[mt*4+3] += (accD[mt][g][3]+bb.w)*wgt;
      }
    }
  }

  // ---- pooled reduction over 16 cols; per-wave partials -> block sum ----
  for (int m = 1; m < 16; m <<= 1)
    for (int i = 0; i < 16; ++i)
      oacc[i] += __shfl_xor(oacc[i], m, 64);
  if (col == 0){
    float* pw = (float*)wr;
    for (int mt = 0; mt < 4; ++mt)
      for (int r = 0; r < 4; ++r)
        pw[mt*16 + quad*4 + r] = oacc[mt*4 + r];
  }
  __syncthreads();                         // barrier 5
  int b = blockIdx.x >> 2;                 // 4 blocks per batch row
  if (tid < 64){
    float s = *(const float*)(wreg + tid*4)        + *(const float*)(wreg + 3328 + tid*4)
            + *(const float*)(wreg + 6656 + tid*4) + *(const float*)(wreg + 9984 + tid*4);
    atomicAdd(&z[b*64 + tid], s);
  }
  if (tid < 4){ atomicAdd(&cnt[tid], lgc[tid]); atomicAdd(&psum[tid], lgp[tid]); }
}

// ================= kFinal: mean pool + LayerNorm + classifier (+aux) ==================
__global__ __launch_bounds__(64) void kFinal(
    const float* __restrict__ z, const u32* __restrict__ cnt, const float* __restrict__ psum,
    const float* __restrict__ ln_g, const float* __restrict__ ln_b,
    const float* __restrict__ cw1, const float* __restrict__ cb1,
    const float* __restrict__ cw2, const float* __restrict__ cb2,
    float* __restrict__ out)
{
  __shared__ float z_l[64], zn_l[64], c1_l[64], red[2];
  int tid = threadIdx.x, b = blockIdx.x;
  z_l[tid] = z[b*64 + tid] * (1.0f/1024.0f);
  __syncthreads();
  if (tid == 0){
    float mu = 0.f; for (int i=0;i<64;++i) mu += z_l[i]; mu *= (1.f/64.f);
    float vv = 0.f; for (int i=0;i<64;++i){ float d=z_l[i]-mu; vv += d*d; } vv *= (1.f/64.f);
    red[0]=mu; red[1]=1.0f/sqrtf(vv+1e-5f);
  }
  __syncthreads();
  zn_l[tid] = (z_l[tid]-red[0])*red[1]*ln_g[tid] + ln_b[tid];
  __syncthreads();
  float a1 = cb1[tid];
  for (int k=0;k<64;++k) a1 += zn_l[k]*cw1[k*64+tid];
  c1_l[tid] = geluf(a1);
  __syncthreads();
  if (tid < 10){
    float y = cb2[tid];
    for (int k=0;k<64;++k) y += c1_l[k]*cw2[k*10+tid];
    out[b*10+tid] = y;
  }
  if (b == 0 && tid == 0){
    float aux = 0.f;
    for (int e=0;e<4;++e) aux += (float)cnt[e]*psum[e];
    out[1280] = 4.0f*aux/(131072.0f*131072.0f);
  }
}

// ================= fallback path (verified R3 fp32 kernels) ===========================
__global__ __launch_bounds__(256) void kInitF(float* z, u32* cnt, float* psum){
  int i = blockIdx.x*256 + threadIdx.x;
  if (i < 8192) z[i] = 0.f;
  if (i < 4){ cnt[i] = 0u; psum[i] = 0.f; }
}

__global__ __launch_bounds__(256) void kFusedF(
    const float* __restrict__ x,
    const float* __restrict__ w1, const float* __restrict__ b1,
    const float* __restrict__ w2, const float* __restrict__ b2,
    const float* __restrict__ gw, const float* __restrict__ gb,
    const float* __restrict__ e1, const float* __restrict__ eb1,
    const float* __restrict__ e2, const float* __restrict__ eb2,
    float* __restrict__ z, u32* __restrict__ cnt, float* __restrict__ psum)
{
  __shared__ float xs[4][192];
  __shared__ float h1s[4][64];
  __shared__ float hs[4][64];
  __shared__ float hid[4][256];
  __shared__ float lg[4][4];
  __shared__ int   be_s[4];
  __shared__ float gv_s[4];
  __shared__ float lgp[4];
  __shared__ u32   lgc[4];
  const int tid  = threadIdx.x;
  const int w    = tid >> 6, lane = tid & 63;
  const int tok  = blockIdx.x*4 + w;
  if (tid < 4){ lgp[tid] = 0.f; lgc[tid] = 0u; }
  for (int r = 0; r < 3; ++r)
    xs[w][lane + 64*r] = x[(size_t)tok*192 + lane + 64*r];
  __syncthreads();
  float a = b1[lane];
  for (int k = 0; k < 192; ++k) a += xs[w][k]*w1[k*64 + lane];
  h1s[w][lane] = geluf(a);
  __syncthreads();
  float h = b2[lane];
  for (int k = 0; k < 64; ++k) h += h1s[w][k]*w2[k*64 + lane];
  hs[w][lane] = h;
  __syncthreads();
  if (lane < 4){
    float l = gb[lane];
    for (int k = 0; k < 64; ++k) l += hs[w][k]*gw[k*4 + lane];
    lg[w][lane] = l;
  }
  __syncthreads();
  if (lane == 0){
    float l0=lg[w][0], l1=lg[w][1], l2=lg[w][2], l3=lg[w][3];
    float mx = fmaxf(fmaxf(l0,l1),fmaxf(l2,l3));
    float x0=expf(l0-mx), x1=expf(l1-mx), x2=expf(l2-mx), x3=expf(l3-mx);
    float inv = 1.f/(x0+x1+x2+x3);
    float p0=x0*inv, p1=x1*inv, p2=x2*inv, p3=x3*inv;
    int be=0; float bv=l0;
    if (l1>bv){bv=l1;be=1;}
    if (l2>bv){bv=l2;be=2;}
    if (l3>bv){bv=l3;be=3;}
    be_s[w]=be;
    gv_s[w]=(be==0)?p0:(be==1)?p1:(be==2)?p2:p3;
    atomicAdd(&lgp[0],p0); atomicAdd(&lgp[1],p1);
    atomicAdd(&lgp[2],p2); atomicAdd(&lgp[3],p3);
    atomicAdd(&lgc[be],1u);
  }
  __syncthreads();
  const int e    = be_s[w];
  const float gv = gv_s[w];
  const float* W1 = e1 + e*16384;
  const float* W2 = e2 + e*16384;
  for (int q = 0; q < 4; ++q){
    int j = q*64 + lane;
    float s = eb1[e*256 + j];
    for (int k = 0; k < 64; ++k) s += hs[w][k]*W1[k*256 + j];
    hid[w][j] = geluf(s);
  }
  __syncthreads();
  float o = eb2[e*64 + lane];
  for (int j = 0; j < 256; ++j) o += hid[w][j]*W2[j*64 + lane];
  int b = tok >> 10;
  atomicAdd(&z[b*64 + lane], o*gv);
  __syncthreads();
  if (tid < 4){ atomicAdd(&cnt[tid], lgc[tid]); atomicAdd(&psum[tid], lgp[tid]); }
}

// ======================================================================================
extern "C" void kernel_launch(void* const* d_in, const int* in_sizes, int n_in,
                              void* d_out, int out_size, void* d_ws, size_t ws_size,
                              hipStream_t stream)
{
  const float* x    = (const float*)d_in[0];
  const float* pw1  = (const float*)d_in[1];
  const float* pb1  = (const float*)d_in[2];
  const float* pw2  = (const float*)d_in[3];
  const float* pb2  = (const float*)d_in[4];
  const float* gw   = (const float*)d_in[5];
  const float* gb   = (const float*)d_in[6];
  const float* ew1  = (const float*)d_in[7];
  const float* eb1  = (const float*)d_in[8];
  const float* ew2  = (const float*)d_in[9];
  const float* eb2  = (const float*)d_in[10];
  const float* lng  = (const float*)d_in[11];
  const float* lnb  = (const float*)d_in[12];
  const float* cw1  = (const float*)d_in[13];
  const float* cb1  = (const float*)d_in[14];
  const float* cw2  = (const float*)d_in[15];
  const float* cb2  = (const float*)d_in[16];
  char* ws  = (char*)d_ws;
  float* out = (float*)d_out;

  if (ws_size >= FAST_WS_BYTES){
    u16*  w1p  = (u16*)(ws + W1P_OFF);
    u16*  w2p  = (u16*)(ws + W2P_OFF);
    u16*  gwp  = (u16*)(ws + GWP_OFF);
    u16*  e1p  = (u16*)(ws + E1P_OFF);
    u16*  e2p  = (u16*)(ws + E2P_OFF);
    float* z    = (float*)(ws + ZF_OFF);
    u32*  cnt  = (u32*)(ws + CNTF_OFF);
    float* psum = (float*)(ws + PSUMF_OFF);
    k0_pack<<<105, 256, 0, stream>>>(pw1, pw2, gw, ew1, ew2,
                                     w1p, w2p, gwp, e1p, e2p, z, cnt, psum);
    kMain <<<512, 256, 0, stream>>>(x, pb1, pb2, gb, w1p, w2p, gwp, e1p, e2p,
                                    eb1, eb2, z, cnt, psum);
    kFinal<<<128, 64, 0, stream>>>(z, cnt, psum, lng, lnb, cw1, cb1, cw2, cb2, out);
  } else {
    float* z    = (float*)(ws + Z_OFF);
    u32*   cnt  = (u32*)(ws + CNT_OFF);
    float* psum = (float*)(ws + PSUM_OFF);
    kInitF <<<32,    256, 0, stream>>>(z, cnt, psum);
    kFusedF<<<32768, 256, 0, stream>>>(x, pw1, pb1, pw2, pb2, gw, gb,
                                       ew1, eb1, ew2, eb2, z, cnt, psum);
    kFinal <<<128,   64,  0, stream>>>(z, cnt, psum, lng, lnb, cw1, cb1, cw2, cb2, out);
  }
}